// Round 1
// baseline (540.662 us; speedup 1.0000x reference)
//
#include <hip/hip_runtime.h>
#include <hip/hip_bf16.h>

#define BT 1024
#define DD 1024
#define HH 2048
#define OO 1024
#define EE 8

typedef __bf16 bf16x8 __attribute__((ext_vector_type(8)));
typedef float  f32x4  __attribute__((ext_vector_type(4)));

// ---------------- workspace layout (bytes) ----------------
// counts : int[8]        @ 0
// off    : int[9]        @ 256     (row offsets padded to 128)
// tok_e  : int[2048]     @ 1024
// tok_p  : int[2048]     @ 9216
// tok_w  : float[2048]   @ 17408
// elist  : int[8*1024]   @ 25600
// Xg     : bf16[3072*1024]  @ 65536
// H1     : bf16[3072*2048]  @ 6356992
// H2     : bf16[3072*2048]  @ 18939904
// Y      : f32 [3072*1024]  @ 31522816   (end ~44.1 MB)

// ---------------- router: logits -> softmax -> top2 -> renorm ----------------
__global__ __launch_bounds__(256) void router_kernel(
    const float* __restrict__ x, const float* __restrict__ Wr, const float* __restrict__ br,
    int* __restrict__ counts, int* __restrict__ elist,
    int* __restrict__ tok_e, int* __restrict__ tok_p, float* __restrict__ tok_w)
{
    int b = blockIdx.x;
    int tid = threadIdx.x;
    float acc[EE];
#pragma unroll
    for (int e = 0; e < EE; ++e) acc[e] = 0.f;
    const float* xr = x + (size_t)b * DD;
    for (int d = tid; d < DD; d += 256) {
        float xv = xr[d];
#pragma unroll
        for (int e = 0; e < EE; ++e) acc[e] += xv * Wr[d * EE + e];
    }
    __shared__ float red[4][EE];
    int lane = tid & 63, wv = tid >> 6;
#pragma unroll
    for (int e = 0; e < EE; ++e) {
        float v = acc[e];
#pragma unroll
        for (int o = 32; o > 0; o >>= 1) v += __shfl_down(v, o, 64);
        if (lane == 0) red[wv][e] = v;
    }
    __syncthreads();
    if (tid == 0) {
        float lg[EE];
#pragma unroll
        for (int e = 0; e < EE; ++e) lg[e] = red[0][e] + red[1][e] + red[2][e] + red[3][e] + br[e];
        float mx = lg[0];
#pragma unroll
        for (int e = 1; e < EE; ++e) mx = fmaxf(mx, lg[e]);
        float s = 0.f, p[EE];
#pragma unroll
        for (int e = 0; e < EE; ++e) { p[e] = expf(lg[e] - mx); s += p[e]; }
        float inv = 1.f / s;
#pragma unroll
        for (int e = 0; e < EE; ++e) p[e] *= inv;
        int i0 = 0; float b0 = p[0];
#pragma unroll
        for (int e = 1; e < EE; ++e) if (p[e] > b0) { b0 = p[e]; i0 = e; }
        int i1 = -1; float b1v = -1.f;
#pragma unroll
        for (int e = 0; e < EE; ++e) if (e != i0 && p[e] > b1v) { b1v = p[e]; i1 = e; }
        float s2 = b0 + b1v + 1e-6f;
        float w0 = b0 / s2, w1 = b1v / s2;
        int p0 = atomicAdd(&counts[i0], 1);
        int p1 = atomicAdd(&counts[i1], 1);
        elist[i0 * 1024 + p0] = b;
        elist[i1 * 1024 + p1] = b;
        tok_e[2 * b] = i0; tok_e[2 * b + 1] = i1;
        tok_p[2 * b] = p0; tok_p[2 * b + 1] = p1;
        tok_w[2 * b] = w0; tok_w[2 * b + 1] = w1;
    }
}

// ---------------- padded prefix sum of counts ----------------
__global__ void offsets_kernel(const int* __restrict__ counts, int* __restrict__ off)
{
    if (threadIdx.x == 0 && blockIdx.x == 0) {
        int a = 0;
        for (int e = 0; e < EE; ++e) {
            off[e] = a;
            a += ((counts[e] + 127) >> 7) << 7;   // pad each expert region to 128 rows
        }
        off[EE] = a;
    }
}

// ---------------- gather x rows -> bf16, pad rows zeroed ----------------
__global__ __launch_bounds__(256) void gather_kernel(
    const float* __restrict__ x, const int* __restrict__ counts, const int* __restrict__ off,
    const int* __restrict__ elist, __bf16* __restrict__ Xg)
{
    int e = blockIdx.y, chunk = blockIdx.x;
    int cnt = counts[e];
    if (chunk * 128 >= cnt) return;
    int base = off[e] + chunk * 128;
    int tid = threadIdx.x;
    for (int it = 0; it < 128; ++it) {          // row = it, col4 = tid
        int slot = chunk * 128 + it;
        __bf16 v[4];
        if (slot < cnt) {
            int tok = elist[e * 1024 + slot];
            const float4 f = *(const float4*)(x + (size_t)tok * DD + tid * 4);
            v[0] = (__bf16)f.x; v[1] = (__bf16)f.y; v[2] = (__bf16)f.z; v[3] = (__bf16)f.w;
        } else {
            v[0] = v[1] = v[2] = v[3] = (__bf16)0.f;
        }
        *(uint2*)(Xg + (size_t)(base + it) * DD + tid * 4) = *(uint2*)v;
    }
}

// ---------------- MFMA GEMM: C[rows,N] = A[rows,K](bf16) * W[e][K,N](fp32) + bias ----------
// RELU_BF16: 1 -> relu + bf16 out, 0 -> fp32 out (no relu)
template <int K, int N, int RELU_BF16>
__global__ __launch_bounds__(256) void gemm_kernel(
    const __bf16* __restrict__ A, const float* __restrict__ Wall,
    const float* __restrict__ bias, void* __restrict__ Cout,
    const int* __restrict__ counts, const int* __restrict__ off)
{
    int e = blockIdx.z, mt = blockIdx.y, nt = blockIdx.x;
    int cnt = counts[e];
    if (mt * 128 >= cnt) return;
    int row0 = off[e] + mt * 128;
    const float* W = Wall + (size_t)e * K * N + nt * 128;
    const __bf16* Ab = A + (size_t)row0 * K;

    __shared__ __bf16 As[128 * 32];   // [m][k], stride 32
    __shared__ __bf16 Bs[128 * 40];   // [n][k], stride 40 (bank-balanced, 16B aligned rows)

    int tid = threadIdx.x;
    int wave = tid >> 6, lane = tid & 63;
    int m = lane & 15, q = lane >> 4;
    int wm = (wave >> 1) * 64, wn = (wave & 1) * 64;

    f32x4 acc[4][4] = {};

    int bn = tid & 127;            // B-stage: column owned by this thread
    int bkc = (tid >> 7) * 16;     // B-stage: k-chunk (0 or 16)

    for (int k0 = 0; k0 < K; k0 += 32) {
        // stage A: 128x32 bf16, 2 x 16B per thread
#pragma unroll
        for (int s = 0; s < 2; ++s) {
            int chunk = tid + s * 256;
            int r = chunk >> 2, c8 = (chunk & 3) * 8;
            uint4 av = *(const uint4*)(Ab + (size_t)r * K + k0 + c8);
            *(uint4*)(&As[r * 32 + c8]) = av;
        }
        // stage B (transposed): each thread reads 16 fp32 down one column (coalesced across
        // lanes per k-row), converts, writes two k-contiguous 16B chunks.
        {
            __bf16 tmp[16];
#pragma unroll
            for (int g = 0; g < 16; ++g) {
                float f = W[(size_t)(k0 + bkc + g) * N + bn];
                tmp[g] = (__bf16)f;
            }
            *(uint4*)(&Bs[bn * 40 + bkc]) = *(uint4*)&tmp[0];
            *(uint4*)(&Bs[bn * 40 + bkc + 8]) = *(uint4*)&tmp[8];
        }
        __syncthreads();

        bf16x8 af[4], bfr[4];
#pragma unroll
        for (int i = 0; i < 4; ++i)
            af[i] = *(bf16x8*)(&As[(wm + i * 16 + m) * 32 + q * 8]);
#pragma unroll
        for (int j = 0; j < 4; ++j)
            bfr[j] = *(bf16x8*)(&Bs[(wn + j * 16 + m) * 40 + q * 8]);
#pragma unroll
        for (int i = 0; i < 4; ++i)
#pragma unroll
            for (int j = 0; j < 4; ++j)
                acc[i][j] = __builtin_amdgcn_mfma_f32_16x16x32_bf16(af[i], bfr[j], acc[i][j], 0, 0, 0);
        __syncthreads();
    }

    // epilogue: D[row = q*4 + r][col = m] per 16x16 subtile
    int colbase = nt * 128 + wn;
#pragma unroll
    for (int j = 0; j < 4; ++j) {
        int col = colbase + j * 16 + m;
        float bv = bias[(size_t)e * N + col];
#pragma unroll
        for (int i = 0; i < 4; ++i) {
            int rbase = row0 + wm + i * 16 + q * 4;
#pragma unroll
            for (int r = 0; r < 4; ++r) {
                float v = acc[i][j][r] + bv;
                if (RELU_BF16) {
                    v = fmaxf(v, 0.f);
                    ((__bf16*)Cout)[(size_t)(rbase + r) * N + col] = (__bf16)v;
                } else {
                    ((float*)Cout)[(size_t)(rbase + r) * N + col] = v;
                }
            }
        }
    }
}

// ---------------- combine: out[b] = w0*Y[r0] + w1*Y[r1] ----------------
__global__ __launch_bounds__(256) void combine_kernel(
    const float* __restrict__ Y, const int* __restrict__ off,
    const int* __restrict__ tok_e, const int* __restrict__ tok_p,
    const float* __restrict__ tok_w, float* __restrict__ out)
{
    int b = blockIdx.x, t = threadIdx.x;
    int e0 = tok_e[2 * b], e1 = tok_e[2 * b + 1];
    int r0 = off[e0] + tok_p[2 * b];
    int r1 = off[e1] + tok_p[2 * b + 1];
    float w0 = tok_w[2 * b], w1 = tok_w[2 * b + 1];
    float4 a = *(const float4*)(Y + (size_t)r0 * OO + t * 4);
    float4 c = *(const float4*)(Y + (size_t)r1 * OO + t * 4);
    float4 o;
    o.x = w0 * a.x + w1 * c.x;
    o.y = w0 * a.y + w1 * c.y;
    o.z = w0 * a.z + w1 * c.z;
    o.w = w0 * a.w + w1 * c.w;
    *(float4*)(out + (size_t)b * OO + t * 4) = o;
}

extern "C" void kernel_launch(void* const* d_in, const int* in_sizes, int n_in,
                              void* d_out, int out_size, void* d_ws, size_t ws_size,
                              hipStream_t stream)
{
    (void)in_sizes; (void)n_in; (void)out_size; (void)ws_size;
    const float* x  = (const float*)d_in[0];
    const float* Wr = (const float*)d_in[1];
    const float* br = (const float*)d_in[2];
    const float* W1 = (const float*)d_in[3];
    const float* b1 = (const float*)d_in[4];
    const float* W2 = (const float*)d_in[5];
    const float* b2 = (const float*)d_in[6];
    const float* W3 = (const float*)d_in[7];
    const float* b3 = (const float*)d_in[8];
    float* out = (float*)d_out;

    char* ws = (char*)d_ws;
    int*    counts = (int*)(ws + 0);
    int*    off    = (int*)(ws + 256);
    int*    tok_e  = (int*)(ws + 1024);
    int*    tok_p  = (int*)(ws + 9216);
    float*  tok_w  = (float*)(ws + 17408);
    int*    elist  = (int*)(ws + 25600);
    __bf16* Xg     = (__bf16*)(ws + 65536);
    __bf16* H1     = (__bf16*)(ws + 6356992);
    __bf16* H2     = (__bf16*)(ws + 18939904);
    float*  Y      = (float*)(ws + 31522816);

    hipMemsetAsync(counts, 0, 256, stream);
    router_kernel<<<1024, 256, 0, stream>>>(x, Wr, br, counts, elist, tok_e, tok_p, tok_w);
    offsets_kernel<<<1, 64, 0, stream>>>(counts, off);
    gather_kernel<<<dim3(8, 8), 256, 0, stream>>>(x, counts, off, elist, Xg);
    gemm_kernel<1024, 2048, 1><<<dim3(16, 8, 8), 256, 0, stream>>>(Xg, W1, b1, (void*)H1, counts, off);
    gemm_kernel<2048, 2048, 1><<<dim3(16, 8, 8), 256, 0, stream>>>(H1, W2, b2, (void*)H2, counts, off);
    gemm_kernel<2048, 1024, 0><<<dim3(8, 8, 8), 256, 0, stream>>>(H2, W3, b3, (void*)Y, counts, off);
    combine_kernel<<<1024, 256, 0, stream>>>(Y, off, tok_e, tok_p, tok_w, out);
}

// Round 2
// 507.607 us; speedup vs baseline: 1.0651x; 1.0651x over previous
//
#include <hip/hip_runtime.h>
#include <hip/hip_bf16.h>

#define BT 1024
#define DD 1024
#define HH 2048
#define OO 1024
#define EE 8

typedef __bf16 bf16x8 __attribute__((ext_vector_type(8)));
typedef float  f32x4  __attribute__((ext_vector_type(4)));

// async global -> LDS, 16 bytes per lane. LDS dest must be wave-uniform base + lane*16.
__device__ __forceinline__ void cp16(void* l, const void* g) {
    __builtin_amdgcn_global_load_lds(
        (const __attribute__((address_space(1))) void*)g,
        (__attribute__((address_space(3))) void*)l, 16, 0, 0);
}

// ---------------- workspace layout (bytes) ----------------
// counts : int[8]            @ 0
// off    : int[9]            @ 256
// tok_e  : int[2048]         @ 1024
// tok_p  : int[2048]         @ 9216
// tok_w  : float[2048]       @ 17408
// elist  : int[8*1024]       @ 25600
// Xg     : bf16[3072*1024]   @ 65536       (end 6356992)
// H1     : bf16[3072*2048]   @ 6356992     (end 18939904)
// H2     : bf16[3072*2048]   @ 18939904    (end 31522816)
// Y      : f32 [3072*1024]   @ 31522816    (end 44105728)
// Wb1    : bf16[8*2048*1024] @ 44105728    (end 77660160)    [e][n][k]
// Wb2    : bf16[8*2048*2048] @ 77660160    (end 144769024)
// Wb3    : bf16[8*1024*2048] @ 144769024   (end 178323456)
#define WS_BIG 178323456ull

// ---------------- router: logits -> softmax -> top2 -> renorm ----------------
__global__ __launch_bounds__(256) void router_kernel(
    const float* __restrict__ x, const float* __restrict__ Wr, const float* __restrict__ br,
    int* __restrict__ counts, int* __restrict__ elist,
    int* __restrict__ tok_e, int* __restrict__ tok_p, float* __restrict__ tok_w)
{
    int b = blockIdx.x;
    int tid = threadIdx.x;
    float acc[EE];
#pragma unroll
    for (int e = 0; e < EE; ++e) acc[e] = 0.f;
    const float* xr = x + (size_t)b * DD;
    for (int d = tid; d < DD; d += 256) {
        float xv = xr[d];
#pragma unroll
        for (int e = 0; e < EE; ++e) acc[e] += xv * Wr[d * EE + e];
    }
    __shared__ float red[4][EE];
    int lane = tid & 63, wv = tid >> 6;
#pragma unroll
    for (int e = 0; e < EE; ++e) {
        float v = acc[e];
#pragma unroll
        for (int o = 32; o > 0; o >>= 1) v += __shfl_down(v, o, 64);
        if (lane == 0) red[wv][e] = v;
    }
    __syncthreads();
    if (tid == 0) {
        float lg[EE];
#pragma unroll
        for (int e = 0; e < EE; ++e) lg[e] = red[0][e] + red[1][e] + red[2][e] + red[3][e] + br[e];
        float mx = lg[0];
#pragma unroll
        for (int e = 1; e < EE; ++e) mx = fmaxf(mx, lg[e]);
        float s = 0.f, p[EE];
#pragma unroll
        for (int e = 0; e < EE; ++e) { p[e] = expf(lg[e] - mx); s += p[e]; }
        float inv = 1.f / s;
#pragma unroll
        for (int e = 0; e < EE; ++e) p[e] *= inv;
        int i0 = 0; float b0 = p[0];
#pragma unroll
        for (int e = 1; e < EE; ++e) if (p[e] > b0) { b0 = p[e]; i0 = e; }
        int i1 = -1; float b1v = -1.f;
#pragma unroll
        for (int e = 0; e < EE; ++e) if (e != i0 && p[e] > b1v) { b1v = p[e]; i1 = e; }
        float s2 = b0 + b1v + 1e-6f;
        float w0 = b0 / s2, w1 = b1v / s2;
        int p0 = atomicAdd(&counts[i0], 1);
        int p1 = atomicAdd(&counts[i1], 1);
        elist[i0 * 1024 + p0] = b;
        elist[i1 * 1024 + p1] = b;
        tok_e[2 * b] = i0; tok_e[2 * b + 1] = i1;
        tok_p[2 * b] = p0; tok_p[2 * b + 1] = p1;
        tok_w[2 * b] = w0; tok_w[2 * b + 1] = w1;
    }
}

// ---------------- padded prefix sum of counts ----------------
__global__ void offsets_kernel(const int* __restrict__ counts, int* __restrict__ off)
{
    if (threadIdx.x == 0 && blockIdx.x == 0) {
        int a = 0;
        for (int e = 0; e < EE; ++e) {
            off[e] = a;
            a += ((counts[e] + 127) >> 7) << 7;
        }
        off[EE] = a;
    }
}

// ---------------- gather x rows -> bf16, pad rows zeroed ----------------
__global__ __launch_bounds__(256) void gather_kernel(
    const float* __restrict__ x, const int* __restrict__ counts, const int* __restrict__ off,
    const int* __restrict__ elist, __bf16* __restrict__ Xg)
{
    int e = blockIdx.y;
    int chunk = blockIdx.x >> 2;      // 128-row chunk
    int rg = blockIdx.x & 3;          // 32-row group within chunk
    int cnt = counts[e];
    if (chunk * 128 >= cnt) return;
    int base = off[e] + chunk * 128 + rg * 32;
    int tid = threadIdx.x;
    for (int it = 0; it < 32; ++it) {
        int slot = chunk * 128 + rg * 32 + it;
        __bf16 v[4];
        if (slot < cnt) {
            int tok = elist[e * 1024 + slot];
            const float4 f = *(const float4*)(x + (size_t)tok * DD + tid * 4);
            v[0] = (__bf16)f.x; v[1] = (__bf16)f.y; v[2] = (__bf16)f.z; v[3] = (__bf16)f.w;
        } else {
            v[0] = v[1] = v[2] = v[3] = (__bf16)0.f;
        }
        *(uint2*)(Xg + (size_t)(base + it) * DD + tid * 4) = *(uint2*)v;
    }
}

// ---------------- convert+transpose: W[e][K][N] fp32 -> Wb[e][N][K] bf16 ----------------
__global__ __launch_bounds__(256) void convert_kernel(
    const float* __restrict__ W, __bf16* __restrict__ Wb, int K, int N)
{
    int e = blockIdx.z;
    int k0 = blockIdx.y * 64, n0 = blockIdx.x * 64;
    const float* Win = W + (size_t)e * K * N;
    __bf16* Wout = Wb + (size_t)e * N * K;
    __shared__ __bf16 T[64 * 72];     // [n][k], stride 72 (even -> 16B-aligned b128 reads)
    int tid = threadIdx.x;
    int kr = tid >> 4;                // 0..15
    int nc = (tid & 15) * 4;
#pragma unroll
    for (int p = 0; p < 4; ++p) {
        int kk = p * 16 + kr;
        float4 v = *(const float4*)(Win + (size_t)(k0 + kk) * N + n0 + nc);
        T[(nc + 0) * 72 + kk] = (__bf16)v.x;
        T[(nc + 1) * 72 + kk] = (__bf16)v.y;
        T[(nc + 2) * 72 + kk] = (__bf16)v.z;
        T[(nc + 3) * 72 + kk] = (__bf16)v.w;
    }
    __syncthreads();
    int nr = tid >> 3;                // 0..31
    int cc = (tid & 7) * 8;
#pragma unroll
    for (int p = 0; p < 2; ++p) {
        int n = p * 32 + nr;
        *(uint4*)(Wout + (size_t)(n0 + n) * K + k0 + cc) = *(uint4*)&T[n * 72 + cc];
    }
}

// ---------------- MFMA GEMM (DMA path): C[rows,N] = A[rows,K] * Wb[e][n][k]^T + bias ------
template <int K, int N, int TN, int RELU_BF16>
__global__ __launch_bounds__(256) void gemm_dma(
    const __bf16* __restrict__ A, const __bf16* __restrict__ Wb,
    const float* __restrict__ bias, void* __restrict__ Cout,
    const int* __restrict__ counts, const int* __restrict__ off)
{
    constexpr int JW = TN / 32;       // 16-wide j-frags per wave
    constexpr int BI = TN / 64;       // B DMA instrs per thread
    int e = blockIdx.z, mt = blockIdx.y, nt = blockIdx.x;
    int cnt = counts[e];
    if (mt * 128 >= cnt) return;
    int row0 = off[e] + mt * 128;
    const __bf16* Ab = A + (size_t)row0 * K;
    const __bf16* Bb = Wb + (size_t)e * N * K + (size_t)(nt * TN) * K;

    __shared__ __bf16 As[128 * 32];   // [m][k] contiguous (DMA lane order)
    __shared__ __bf16 Bs[TN * 32];    // [n][k] contiguous

    int tid = threadIdx.x;
    int wave = tid >> 6, lane = tid & 63;
    int m = lane & 15, q = lane >> 4;
    int wm = (wave >> 1) * 64, wn = (wave & 1) * (TN / 2);

    // DMA mapping: LDS byte addr = (s*4+wave)*1024 + lane*16  <=>  row (s*64+wave*16+lane/4), k8=(lane&3)*8
    int ar = (tid >> 6) * 16 + ((tid & 63) >> 2);
    int k8 = (tid & 3) * 8;

    f32x4 acc[4][JW] = {};

    for (int k0 = 0; k0 < K; k0 += 32) {
#pragma unroll
        for (int s = 0; s < 2; ++s)
            cp16(&As[(s * 64 + ar) * 32 + k8], Ab + (size_t)(s * 64 + ar) * K + k0 + k8);
#pragma unroll
        for (int s = 0; s < BI; ++s)
            cp16(&Bs[(s * 64 + ar) * 32 + k8], Bb + (size_t)(s * 64 + ar) * K + k0 + k8);
        __syncthreads();

        bf16x8 af[4], bfr[JW];
#pragma unroll
        for (int i = 0; i < 4; ++i)
            af[i] = *(bf16x8*)(&As[(wm + i * 16 + m) * 32 + q * 8]);
#pragma unroll
        for (int j = 0; j < JW; ++j)
            bfr[j] = *(bf16x8*)(&Bs[(wn + j * 16 + m) * 32 + q * 8]);
#pragma unroll
        for (int i = 0; i < 4; ++i)
#pragma unroll
            for (int j = 0; j < JW; ++j)
                acc[i][j] = __builtin_amdgcn_mfma_f32_16x16x32_bf16(af[i], bfr[j], acc[i][j], 0, 0, 0);
        __syncthreads();
    }

    int colbase = nt * TN + wn;
#pragma unroll
    for (int j = 0; j < JW; ++j) {
        int col = colbase + j * 16 + m;
        float bv = bias[(size_t)e * N + col];
#pragma unroll
        for (int i = 0; i < 4; ++i) {
            int rbase = row0 + wm + i * 16 + q * 4;
#pragma unroll
            for (int r = 0; r < 4; ++r) {
                float v = acc[i][j][r] + bv;
                if (RELU_BF16) {
                    v = fmaxf(v, 0.f);
                    ((__bf16*)Cout)[(size_t)(rbase + r) * N + col] = (__bf16)v;
                } else {
                    ((float*)Cout)[(size_t)(rbase + r) * N + col] = v;
                }
            }
        }
    }
}

// ---------------- fallback GEMM (round-1, fp32 W in-loop) ----------------
template <int K, int N, int RELU_BF16>
__global__ __launch_bounds__(256) void gemm_fb(
    const __bf16* __restrict__ A, const float* __restrict__ Wall,
    const float* __restrict__ bias, void* __restrict__ Cout,
    const int* __restrict__ counts, const int* __restrict__ off)
{
    int e = blockIdx.z, mt = blockIdx.y, nt = blockIdx.x;
    int cnt = counts[e];
    if (mt * 128 >= cnt) return;
    int row0 = off[e] + mt * 128;
    const float* W = Wall + (size_t)e * K * N + nt * 128;
    const __bf16* Ab = A + (size_t)row0 * K;

    __shared__ __bf16 As[128 * 32];
    __shared__ __bf16 Bs[128 * 40];

    int tid = threadIdx.x;
    int wave = tid >> 6, lane = tid & 63;
    int m = lane & 15, q = lane >> 4;
    int wm = (wave >> 1) * 64, wn = (wave & 1) * 64;

    f32x4 acc[4][4] = {};
    int bn = tid & 127;
    int bkc = (tid >> 7) * 16;

    for (int k0 = 0; k0 < K; k0 += 32) {
#pragma unroll
        for (int s = 0; s < 2; ++s) {
            int chunk = tid + s * 256;
            int r = chunk >> 2, c8 = (chunk & 3) * 8;
            uint4 av = *(const uint4*)(Ab + (size_t)r * K + k0 + c8);
            *(uint4*)(&As[r * 32 + c8]) = av;
        }
        {
            __bf16 tmp[16];
#pragma unroll
            for (int g = 0; g < 16; ++g) {
                float f = W[(size_t)(k0 + bkc + g) * N + bn];
                tmp[g] = (__bf16)f;
            }
            *(uint4*)(&Bs[bn * 40 + bkc]) = *(uint4*)&tmp[0];
            *(uint4*)(&Bs[bn * 40 + bkc + 8]) = *(uint4*)&tmp[8];
        }
        __syncthreads();

        bf16x8 af[4], bfr[4];
#pragma unroll
        for (int i = 0; i < 4; ++i)
            af[i] = *(bf16x8*)(&As[(wm + i * 16 + m) * 32 + q * 8]);
#pragma unroll
        for (int j = 0; j < 4; ++j)
            bfr[j] = *(bf16x8*)(&Bs[(wn + j * 16 + m) * 40 + q * 8]);
#pragma unroll
        for (int i = 0; i < 4; ++i)
#pragma unroll
            for (int j = 0; j < 4; ++j)
                acc[i][j] = __builtin_amdgcn_mfma_f32_16x16x32_bf16(af[i], bfr[j], acc[i][j], 0, 0, 0);
        __syncthreads();
    }

    int colbase = nt * 128 + wn;
#pragma unroll
    for (int j = 0; j < 4; ++j) {
        int col = colbase + j * 16 + m;
        float bv = bias[(size_t)e * N + col];
#pragma unroll
        for (int i = 0; i < 4; ++i) {
            int rbase = row0 + wm + i * 16 + q * 4;
#pragma unroll
            for (int r = 0; r < 4; ++r) {
                float v = acc[i][j][r] + bv;
                if (RELU_BF16) {
                    v = fmaxf(v, 0.f);
                    ((__bf16*)Cout)[(size_t)(rbase + r) * N + col] = (__bf16)v;
                } else {
                    ((float*)Cout)[(size_t)(rbase + r) * N + col] = v;
                }
            }
        }
    }
}

// ---------------- combine: out[b] = w0*Y[r0] + w1*Y[r1] ----------------
__global__ __launch_bounds__(256) void combine_kernel(
    const float* __restrict__ Y, const int* __restrict__ off,
    const int* __restrict__ tok_e, const int* __restrict__ tok_p,
    const float* __restrict__ tok_w, float* __restrict__ out)
{
    int b = blockIdx.x, t = threadIdx.x;
    int e0 = tok_e[2 * b], e1 = tok_e[2 * b + 1];
    int r0 = off[e0] + tok_p[2 * b];
    int r1 = off[e1] + tok_p[2 * b + 1];
    float w0 = tok_w[2 * b], w1 = tok_w[2 * b + 1];
    float4 a = *(const float4*)(Y + (size_t)r0 * OO + t * 4);
    float4 c = *(const float4*)(Y + (size_t)r1 * OO + t * 4);
    float4 o;
    o.x = w0 * a.x + w1 * c.x;
    o.y = w0 * a.y + w1 * c.y;
    o.z = w0 * a.z + w1 * c.z;
    o.w = w0 * a.w + w1 * c.w;
    *(float4*)(out + (size_t)b * OO + t * 4) = o;
}

extern "C" void kernel_launch(void* const* d_in, const int* in_sizes, int n_in,
                              void* d_out, int out_size, void* d_ws, size_t ws_size,
                              hipStream_t stream)
{
    (void)in_sizes; (void)n_in; (void)out_size;
    const float* x  = (const float*)d_in[0];
    const float* Wr = (const float*)d_in[1];
    const float* br = (const float*)d_in[2];
    const float* W1 = (const float*)d_in[3];
    const float* b1 = (const float*)d_in[4];
    const float* W2 = (const float*)d_in[5];
    const float* b2 = (const float*)d_in[6];
    const float* W3 = (const float*)d_in[7];
    const float* b3 = (const float*)d_in[8];
    float* out = (float*)d_out;

    char* ws = (char*)d_ws;
    int*    counts = (int*)(ws + 0);
    int*    off    = (int*)(ws + 256);
    int*    tok_e  = (int*)(ws + 1024);
    int*    tok_p  = (int*)(ws + 9216);
    float*  tok_w  = (float*)(ws + 17408);
    int*    elist  = (int*)(ws + 25600);
    __bf16* Xg     = (__bf16*)(ws + 65536);
    __bf16* H1     = (__bf16*)(ws + 6356992);
    __bf16* H2     = (__bf16*)(ws + 18939904);
    float*  Y      = (float*)(ws + 31522816);
    __bf16* Wb1    = (__bf16*)(ws + 44105728);
    __bf16* Wb2    = (__bf16*)(ws + 77660160);
    __bf16* Wb3    = (__bf16*)(ws + 144769024);

    const bool big = (ws_size >= WS_BIG);   // call-invariant -> graph-safe

    hipMemsetAsync(counts, 0, 256, stream);
    router_kernel<<<1024, 256, 0, stream>>>(x, Wr, br, counts, elist, tok_e, tok_p, tok_w);
    offsets_kernel<<<1, 64, 0, stream>>>(counts, off);
    gather_kernel<<<dim3(32, 8), 256, 0, stream>>>(x, counts, off, elist, Xg);

    if (big) {
        convert_kernel<<<dim3(HH / 64, DD / 64, EE), 256, 0, stream>>>(W1, Wb1, DD, HH);
        convert_kernel<<<dim3(HH / 64, HH / 64, EE), 256, 0, stream>>>(W2, Wb2, HH, HH);
        convert_kernel<<<dim3(OO / 64, HH / 64, EE), 256, 0, stream>>>(W3, Wb3, HH, OO);
        gemm_dma<1024, 2048, 128, 1><<<dim3(16, 8, 8), 256, 0, stream>>>(Xg, Wb1, b1, (void*)H1, counts, off);
        gemm_dma<2048, 2048, 128, 1><<<dim3(16, 8, 8), 256, 0, stream>>>(H1, Wb2, b2, (void*)H2, counts, off);
        gemm_dma<2048, 1024, 64, 0><<<dim3(16, 8, 8), 256, 0, stream>>>(H2, Wb3, b3, (void*)Y, counts, off);
    } else {
        gemm_fb<1024, 2048, 1><<<dim3(16, 8, 8), 256, 0, stream>>>(Xg, W1, b1, (void*)H1, counts, off);
        gemm_fb<2048, 2048, 1><<<dim3(16, 8, 8), 256, 0, stream>>>(H1, W2, b2, (void*)H2, counts, off);
        gemm_fb<2048, 1024, 0><<<dim3(8, 8, 8), 256, 0, stream>>>(H2, W3, b3, (void*)Y, counts, off);
    }
    combine_kernel<<<1024, 256, 0, stream>>>(Y, off, tok_e, tok_p, tok_w, out);
}